// Round 2
// baseline (1509.804 us; speedup 1.0000x reference)
//
#include <hip/hip_runtime.h>
#include <cstdint>
#include <cstddef>

#define DI __device__ __forceinline__

typedef unsigned short u16;
typedef u16 u16x8 __attribute__((ext_vector_type(8)));
typedef u16 u16x4 __attribute__((ext_vector_type(4)));
typedef float f32x4 __attribute__((ext_vector_type(4)));
typedef __bf16 bf16x8 __attribute__((ext_vector_type(8)));

constexpr float EPSf  = 1e-5f;
constexpr float SCALE = 1.0f / (5.656854249492381f * 256.0f); // 1/(sqrt(32)*H*W)

DI float bf2f(u16 u) { union { uint32_t i; float f; } v; v.i = ((uint32_t)u) << 16; return v.f; }
DI u16 f2bf(float f) {
    union { float f; uint32_t i; } v; v.f = f;
    uint32_t r = v.i + 0x7fffu + ((v.i >> 16) & 1u);
    return (u16)(r >> 16);
}

DI f32x4 MFMA(bf16x8 a, bf16x8 b, f32x4 c) {
    return __builtin_amdgcn_mfma_f32_16x16x32_bf16(a, b, c, 0, 0, 0);
}

DI int region3(int x) { return x < 12 ? 0 : (x < 14 ? 1 : 2); }

// fast tanh-gelu: 0.5x(1+tanh(s(x+0.044715x^3))) == x*sigmoid(2s(x+...))
DI float gelu_f(float x) {
    float u = 1.5957691216f * x * (1.f + 0.044715f * x * x);
    return x * __builtin_amdgcn_rcpf(1.f + __expf(-u));
}

// ---------------------------------------------------------------------------
// KW: transpose 6 weights [c][d] f32 -> WT [d][c] bf16
// ---------------------------------------------------------------------------
__global__ __launch_bounds__(256) void kw_prep(
        const float* __restrict__ w_q, const float* __restrict__ w_k,
        const float* __restrict__ w_v, const float* __restrict__ w_o,
        const float* __restrict__ w1,  const float* __restrict__ w2,
        u16* __restrict__ wt) {
    __shared__ float lds[128 * 129];
    const float* W;
    switch (blockIdx.x) {
        case 0: W = w_q; break; case 1: W = w_k; break; case 2: W = w_v; break;
        case 3: W = w_o; break; case 4: W = w1;  break; default: W = w2;  break;
    }
    u16* O = wt + blockIdx.x * 16384;
    int tid = threadIdx.x;
    for (int i = 0; i < 16; i++) {
        int flat = i * 1024 + tid * 4;
        float4 vv = *(const float4*)(W + flat);
        int c = flat >> 7, d = flat & 127;
        lds[c * 129 + d + 0] = vv.x; lds[c * 129 + d + 1] = vv.y;
        lds[c * 129 + d + 2] = vv.z; lds[c * 129 + d + 3] = vv.w;
    }
    __syncthreads();
    for (int i = 0; i < 32; i++) {
        int flat2 = i * 512 + tid * 2;
        int d = flat2 >> 7, c = flat2 & 127;
        u16 a = f2bf(lds[c * 129 + d]);
        u16 b = f2bf(lds[(c + 1) * 129 + d]);
        uint32_t pk = (uint32_t)a | ((uint32_t)b << 16);
        *(uint32_t*)(O + flat2) = pk;
    }
}

// ---------------------------------------------------------------------------
// K2: per windowed-token: transposed float4 loads + reg-fused InstanceNorm,
//     single conflict-free LDS write, 16-wave GEMM -> Q,K,V bf16 [xy][c].
//     Wave w owns rows 16w..16w+15: A-frags + epilogue staging are wave-local
//     (no barriers after the normalize barrier). B-frags from L2-hot global.
// ---------------------------------------------------------------------------
__global__ __launch_bounds__(1024, 4) void k2_qkv(
        const float* __restrict__ v, const u16* __restrict__ wt,
        const float* __restrict__ b_q, const float* __restrict__ b_k,
        const float* __restrict__ b_v,
        u16* __restrict__ Qg, u16* __restrict__ Kg, u16* __restrict__ Vg) {
    __shared__ __align__(16) u16 Abuf[256 * 136];
    __shared__ float red[2][8][128];
    __shared__ float stats[2][128];

    int tid = threadIdx.x;
    int wtk = blockIdx.x;                       // windowed token id
    int b = wtk >> 8, n = (wtk >> 4) & 15, t = wtk & 15;
    int wi = n >> 2, wj = n & 3, ti = t >> 2, tj = t & 3;
    int si = (wi * 4 + ti + 2) & 15, sj = (wj * 4 + tj + 2) & 15; // roll -2
    const float* src = v + (size_t)(b * 256 + si * 16 + sj) * 32768;

    // transposed load: lane owns channel c, xy = g*32 + xyq*4 + j
    int c = tid & 127, xyq = tid >> 7;
    float vals[32];
    float s = 0.f, q = 0.f;
    #pragma unroll
    for (int g = 0; g < 8; g++) {
        float4 f = *(const float4*)(src + c * 256 + g * 32 + xyq * 4);
        vals[g * 4 + 0] = f.x; vals[g * 4 + 1] = f.y;
        vals[g * 4 + 2] = f.z; vals[g * 4 + 3] = f.w;
        s += f.x + f.y + f.z + f.w;
        q += f.x * f.x + f.y * f.y + f.z * f.z + f.w * f.w;
    }
    red[0][xyq][c] = s; red[1][xyq][c] = q;
    __syncthreads();
    if (tid < 128) {
        float ss = 0.f, qq = 0.f;
        #pragma unroll
        for (int p = 0; p < 8; p++) { ss += red[0][p][tid]; qq += red[1][p][tid]; }
        float mean = ss * (1.f / 256.f);
        float var = qq * (1.f / 256.f) - mean * mean;
        float a = rsqrtf(var + EPSf);
        stats[0][tid] = a; stats[1][tid] = -mean * a;
    }
    __syncthreads();
    float na = stats[0][c], nb = stats[1][c];
    // single conflict-free write pass (consecutive-c b16 stores)
    #pragma unroll
    for (int g = 0; g < 8; g++)
        #pragma unroll
        for (int j = 0; j < 4; j++)
            Abuf[(g * 32 + xyq * 4 + j) * 136 + c] = f2bf(fmaf(vals[g * 4 + j], na, nb));
    __syncthreads();

    // GEMM: wave w owns rows 16w..16w+15
    int wave = tid >> 6, lane = tid & 63;
    int lrow = lane & 15, quad = lane >> 4;
    bf16x8 afr[4];
    #pragma unroll
    for (int kt = 0; kt < 4; kt++)
        afr[kt] = *(const bf16x8*)&Abuf[(wave * 16 + lrow) * 136 + kt * 32 + quad * 8];
    // wave-local rows -> no barrier: stgw region == exactly the rows this wave read
    u16* stgw = Abuf + wave * 2176;    // 16 rows x pitch 136
    for (int w = 0; w < 3; w++) {
        const u16* WTp = wt + w * 16384;
        const float* bias = (w == 0) ? b_q : (w == 1) ? b_k : b_v;
        u16* O = ((w == 0) ? Qg : (w == 1) ? Kg : Vg) + (size_t)wtk * 32768;
        f32x4 acc[8];
        #pragma unroll
        for (int nt = 0; nt < 8; nt++) acc[nt] = (f32x4){0.f, 0.f, 0.f, 0.f};
        #pragma unroll
        for (int kt = 0; kt < 4; kt++) {
            #pragma unroll
            for (int nt = 0; nt < 8; nt++) {
                bf16x8 bfr = *(const bf16x8*)&WTp[(nt * 16 + lrow) * 128 + kt * 32 + quad * 8];
                acc[nt] = MFMA(afr[kt], bfr, acc[nt]);
            }
        }
        #pragma unroll
        for (int nt = 0; nt < 8; nt++) {
            int d = nt * 16 + lrow;
            float bv = bias[d];
            #pragma unroll
            for (int r = 0; r < 4; r++)
                stgw[(quad * 4 + r) * 136 + d] = f2bf(acc[nt][r] + bv);
        }
        // wave-local staging readback -> coalesced 1KB stores
        #pragma unroll
        for (int ro = 0; ro < 4; ro++) {
            int flat = ro * 512 + lane * 8;
            *(u16x8*)&O[wave * 2048 + flat] =
                *(const u16x8*)&stgw[(flat >> 7) * 136 + (flat & 127)];
        }
    }
}

// ---------------------------------------------------------------------------
// K3: partial scores per (b, window, xy-half). Fragments straight from global.
//     16 waves = 4 heads x 4 xy-subchunks; cross-wave f32x4 reduce in LDS.
// ---------------------------------------------------------------------------
__global__ __launch_bounds__(1024, 4) void k3_scores(
        const u16* __restrict__ Qg, const u16* __restrict__ Kg,
        float* __restrict__ spart) {
    __shared__ f32x4 red3[3][4][64];
    int tid = threadIdx.x;
    int bid = blockIdx.x;                   // 256 = b(8) * n(16) * half(2)
    int b = bid >> 5, n = (bid >> 1) & 15, half = bid & 1;
    int wtb = (b * 16 + n) * 16;
    int lane = tid & 63, wave = tid >> 6;   // 16 waves
    int head = wave & 3, sub = wave >> 2;   // head 0..3, xy-subchunk 0..3
    int lrow = lane & 15, quad = lane >> 4;
    int xyb = half * 128 + sub * 32;
    const u16* Qp = Qg + (size_t)(wtb + lrow) * 32768 + (size_t)xyb * 128 + head * 32 + quad * 8;
    const u16* Kp = Kg + (size_t)(wtb + lrow) * 32768 + (size_t)xyb * 128 + head * 32 + quad * 8;
    f32x4 acc = {0.f, 0.f, 0.f, 0.f};
    #pragma unroll 4
    for (int kt = 0; kt < 32; kt++) {
        bf16x8 aq = *(const bf16x8*)(Qp + kt * 128);
        bf16x8 bk = *(const bf16x8*)(Kp + kt * 128);
        acc = MFMA(aq, bk, acc);
    }
    if (sub) red3[sub - 1][head][lane] = acc;
    __syncthreads();
    if (sub == 0) {
        f32x4 a0 = red3[0][head][lane];
        f32x4 a1 = red3[1][head][lane];
        f32x4 a2 = red3[2][head][lane];
        acc = acc + a0 + a1 + a2;
        float* sp = spart + (size_t)(((half * 8 + b) * 16 + n) * 4 + head) * 256;
        for (int r = 0; r < 4; r++) sp[(quad * 4 + r) * 16 + lrow] = acc[r];
    }
}

// ---------------------------------------------------------------------------
// K4: softmax+mask, o = attn*V, Wo GEMM, + residual v -> v2 bf16 [tok][xy][c]
//     16 waves; wave w owns output token t=w; Obuf epilogue staging wave-local.
// ---------------------------------------------------------------------------
__global__ __launch_bounds__(1024, 4) void k4_attnout(
        const float* __restrict__ v, const u16* __restrict__ Vg,
        const float* __restrict__ spart, const u16* __restrict__ wt,
        const float* __restrict__ b_o, u16* __restrict__ v2) {
    __shared__ __align__(16) u16 Vc[32768];       // 64KB: 16 s x 16 xy x 128 c
    __shared__ __align__(16) u16 Obuf[256 * 136]; // o tiles / epilogue staging
    __shared__ float attn[4][16][16];
    int tid = threadIdx.x;
    int bid = blockIdx.x;              // 512
    int b = bid >> 6, n = (bid >> 2) & 15, qtr = bid & 3;
    int wi = n >> 2, wj = n & 3;
    int wtb = (b * 16 + n) * 16;

    if (tid < 64) {
        int h = tid >> 4, t = tid & 15;
        int it = wi * 4 + (t >> 2) , jt = wj * 4 + (t & 3);
        int rt = region3(it) * 3 + region3(jt);
        const float* sp0 = spart + (size_t)(((0 + b) * 16 + n) * 4 + h) * 256 + t * 16;
        const float* sp1 = spart + (size_t)(((8 + b) * 16 + n) * 4 + h) * 256 + t * 16;
        float vals[16]; float mx = -1e30f;
        for (int s = 0; s < 16; s++) {
            int is = wi * 4 + (s >> 2), js = wj * 4 + (s & 3);
            int rs = region3(is) * 3 + region3(js);
            float sc = (sp0[s] + sp1[s]) * SCALE + (rs == rt ? 0.f : -1e9f);
            vals[s] = sc; mx = fmaxf(mx, sc);
        }
        float sum = 0.f;
        for (int s = 0; s < 16; s++) { vals[s] = __expf(vals[s] - mx); sum += vals[s]; }
        float inv = 1.f / sum;
        for (int s = 0; s < 16; s++) attn[h][t][s] = vals[s] * inv;
    }
    __syncthreads();

    int lane = tid & 63, wave = tid >> 6;
    int lrow = lane & 15, quad = lane >> 4;
    const u16* WoT = wt + 3 * 16384;

    for (int sub = 0; sub < 4; sub++) {
        int xyb = qtr * 64 + sub * 16;
        if (sub) __syncthreads();          // prior epilogue reads of Obuf done
        #pragma unroll
        for (int it = 0; it < 4; it++) {
            int flat = (it * 1024 + tid) * 8;
            int s = flat >> 11, rem = flat & 2047;
            *(u16x8*)&Vc[flat] =
                *(const u16x8*)&Vg[(size_t)(wtb + s) * 32768 + xyb * 128 + rem];
        }
        __syncthreads();
        // o-compute (VALU): o[t][xyl][c] = sum_s attn[h][t][s] * V[s][xyl][c]
        {
            int c = tid & 127, xg = tid >> 7;   // xg 0..7
            int h = c >> 5;
            float vreg[2][16];
            #pragma unroll
            for (int rep = 0; rep < 2; rep++) {
                int xyl = xg * 2 + rep;
                #pragma unroll
                for (int s = 0; s < 16; s++)
                    vreg[rep][s] = bf2f(Vc[s * 2048 + xyl * 128 + c]);
            }
            #pragma unroll
            for (int t = 0; t < 16; t++) {
                float oa0 = 0.f, oa1 = 0.f;
                #pragma unroll
                for (int s = 0; s < 16; s++) {
                    float a = attn[h][t][s];
                    oa0 += a * vreg[0][s]; oa1 += a * vreg[1][s];
                }
                Obuf[(t * 16 + xg * 2 + 0) * 136 + c] = f2bf(oa0);
                Obuf[(t * 16 + xg * 2 + 1) * 136 + c] = f2bf(oa1);
            }
        }
        __syncthreads();
        // Wo GEMM + residual; wave w owns token t = w (rows 16w..16w+15)
        bf16x8 afr[4];
        #pragma unroll
        for (int kt = 0; kt < 4; kt++)
            afr[kt] = *(const bf16x8*)&Obuf[(wave * 16 + lrow) * 136 + kt * 32 + quad * 8];
        f32x4 acc[8];
        #pragma unroll
        for (int nt = 0; nt < 8; nt++) acc[nt] = (f32x4){0.f, 0.f, 0.f, 0.f};
        #pragma unroll
        for (int kt = 0; kt < 4; kt++) {
            #pragma unroll
            for (int nt = 0; nt < 8; nt++) {
                bf16x8 bfr = *(const bf16x8*)&WoT[(nt * 16 + lrow) * 128 + kt * 32 + quad * 8];
                acc[nt] = MFMA(afr[kt], bfr, acc[nt]);
            }
        }
        int mt = wave;                  // token t within window
        int sd = (((wi * 4 + (mt >> 2) + 2) & 15) << 4) | ((wj * 4 + (mt & 3) + 2) & 15);
        size_t tokbase = (size_t)(b * 256 + sd) * 32768;
        u16* stgw = Obuf + wave * 2176;   // exactly this wave's afr rows
        #pragma unroll
        for (int nt = 0; nt < 8; nt++) {
            int cc = nt * 16 + lrow;
            float bv = b_o[cc];
            float4 res = *(const float4*)&v[tokbase + (size_t)cc * 256 + xyb + quad * 4];
            stgw[(quad * 4 + 0) * 136 + cc] = f2bf(acc[nt][0] + bv + res.x);
            stgw[(quad * 4 + 1) * 136 + cc] = f2bf(acc[nt][1] + bv + res.y);
            stgw[(quad * 4 + 2) * 136 + cc] = f2bf(acc[nt][2] + bv + res.z);
            stgw[(quad * 4 + 3) * 136 + cc] = f2bf(acc[nt][3] + bv + res.w);
        }
        size_t obase = tokbase + (size_t)xyb * 128;
        #pragma unroll
        for (int ro = 0; ro < 4; ro++) {
            int flat = ro * 512 + lane * 8;
            *(u16x8*)&v2[obase + flat] =
                *(const u16x8*)&stgw[(flat >> 7) * 136 + (flat & 127)];
        }
    }
}

// ---------------------------------------------------------------------------
// K6: per token: norm (reg-fused), W1 GEMM + gelu, W2 GEMM, + residual
//     -> out f32 [c][xy]. 16 waves; H and epilogue are wave-local.
// ---------------------------------------------------------------------------
__global__ __launch_bounds__(1024, 4) void k6_mlp(
        const u16* __restrict__ v2, const u16* __restrict__ wt,
        const float* __restrict__ b1, const float* __restrict__ b2,
        float* __restrict__ out) {
    __shared__ __align__(16) u16 Nbuf[256 * 136];
    __shared__ __align__(16) u16 Hbuf[256 * 136];
    __shared__ float red[2][8][128];
    __shared__ float stats[3][128];
    int tid = threadIdx.x;
    size_t tok = blockIdx.x;
    const u16* src = v2 + tok * 32768;

    // load raw into regs + Nbuf (lane owns 8 consecutive c, 4 xy rows)
    u16x8 ld[4];
    #pragma unroll
    for (int it = 0; it < 4; it++) {
        int flat = (it * 1024 + tid) * 8;
        int xy = flat >> 7, cc = flat & 127;
        ld[it] = *(const u16x8*)&src[flat];
        *(u16x8*)&Nbuf[xy * 136 + cc] = ld[it];
    }
    __syncthreads();
    {
        int c = tid & 127, p = tid >> 7;
        float s = 0.f, q = 0.f;
        for (int k = 0; k < 32; k++) {
            float x = bf2f(Nbuf[(p * 32 + k) * 136 + c]);
            s += x; q += x * x;
        }
        red[0][p][c] = s; red[1][p][c] = q;
    }
    __syncthreads();
    if (tid < 128) {
        int c = tid;
        float s = 0.f, q = 0.f;
        #pragma unroll
        for (int p = 0; p < 8; p++) { s += red[0][p][c]; q += red[1][p][c]; }
        float mean = s * (1.f / 256.f);
        float var = q * (1.f / 256.f) - mean * mean;
        float rstd = rsqrtf(var + EPSf);
        stats[0][c] = mean; stats[1][c] = rstd; stats[2][c] = (var + EPSf) * rstd; // sd
    }
    __syncthreads();
    // normalize in registers, single Nbuf write
    {
        int c0 = (tid & 15) * 8;
        float a[8], bb[8];
        #pragma unroll
        for (int j = 0; j < 8; j++) {
            float m = stats[0][c0 + j], r = stats[1][c0 + j];
            a[j] = r; bb[j] = -m * r;
        }
        #pragma unroll
        for (int it = 0; it < 4; it++) {
            int flat = (it * 1024 + tid) * 8;
            int xy = flat >> 7;
            u16x8 u = ld[it];
            u16x8 o;
            #pragma unroll
            for (int j = 0; j < 8; j++)
                o[j] = f2bf(fmaf(bf2f(u[j]), a[j], bb[j]));
            *(u16x8*)&Nbuf[xy * 136 + c0] = o;
        }
    }
    __syncthreads();

    int wave = tid >> 6, lane = tid & 63;
    int lrow = lane & 15, quad = lane >> 4;
    const u16* W1T = wt + 4 * 16384;
    const u16* W2T = wt + 5 * 16384;

    // GEMM1 + gelu -> Hbuf (wave-local rows 16w..16w+15)
    {
        bf16x8 afr[4];
        #pragma unroll
        for (int kt = 0; kt < 4; kt++)
            afr[kt] = *(const bf16x8*)&Nbuf[(wave * 16 + lrow) * 136 + kt * 32 + quad * 8];
        f32x4 acc[8];
        #pragma unroll
        for (int nt = 0; nt < 8; nt++) acc[nt] = (f32x4){0.f, 0.f, 0.f, 0.f};
        #pragma unroll
        for (int kt = 0; kt < 4; kt++) {
            #pragma unroll
            for (int nt = 0; nt < 8; nt++) {
                bf16x8 bfr = *(const bf16x8*)&W1T[(nt * 16 + lrow) * 128 + kt * 32 + quad * 8];
                acc[nt] = MFMA(afr[kt], bfr, acc[nt]);
            }
        }
        #pragma unroll
        for (int nt = 0; nt < 8; nt++) {
            int c = nt * 16 + lrow;
            float bv = b1[c];
            #pragma unroll
            for (int r = 0; r < 4; r++) {
                float x = acc[nt][r] + bv;
                Hbuf[(wave * 16 + quad * 4 + r) * 136 + c] = f2bf(gelu_f(x));
            }
        }
    }
    // H rows wave-local -> no barrier
    {
        bf16x8 afr[4];
        #pragma unroll
        for (int kt = 0; kt < 4; kt++)
            afr[kt] = *(const bf16x8*)&Hbuf[(wave * 16 + lrow) * 136 + kt * 32 + quad * 8];
        f32x4 acc[8];
        #pragma unroll
        for (int nt = 0; nt < 8; nt++) acc[nt] = (f32x4){0.f, 0.f, 0.f, 0.f};
        #pragma unroll
        for (int kt = 0; kt < 4; kt++) {
            #pragma unroll
            for (int nt = 0; nt < 8; nt++) {
                bf16x8 bfr = *(const bf16x8*)&W2T[(nt * 16 + lrow) * 128 + kt * 32 + quad * 8];
                acc[nt] = MFMA(afr[kt], bfr, acc[nt]);
            }
        }
        #pragma unroll
        for (int nt = 0; nt < 8; nt++) {
            int c = nt * 16 + lrow;
            float mean = stats[0][c], sd = stats[2][c], bv = b2[c];
            f32x4 o4;
            #pragma unroll
            for (int r = 0; r < 4; r++) {
                int m = wave * 16 + quad * 4 + r;
                float n2v = bf2f(Nbuf[m * 136 + c]);
                o4[r] = acc[nt][r] + bv + n2v * sd + mean;
            }
            *(f32x4*)&out[tok * 32768 + (size_t)c * 256 + wave * 16 + quad * 4] = o4;
        }
    }
}

// ---------------------------------------------------------------------------
extern "C" void kernel_launch(void* const* d_in, const int* in_sizes, int n_in,
                              void* d_out, int out_size, void* d_ws, size_t ws_size,
                              hipStream_t stream) {
    const float* v   = (const float*)d_in[0];
    const float* w_q = (const float*)d_in[1];
    const float* b_q = (const float*)d_in[2];
    const float* w_k = (const float*)d_in[3];
    const float* b_k = (const float*)d_in[4];
    const float* w_v = (const float*)d_in[5];
    const float* b_v = (const float*)d_in[6];
    const float* w_o = (const float*)d_in[7];
    const float* b_o = (const float*)d_in[8];
    const float* w1  = (const float*)d_in[9];
    const float* b1  = (const float*)d_in[10];
    const float* w2  = (const float*)d_in[11];
    const float* b2  = (const float*)d_in[12];

    // workspace layout (~135.5 MB):
    //   wt    : [0, 196608)            6 x 128x128 bf16 transposed weights
    //   spart : [196608, 1245184)      2*8*16*4*256 floats = 1 MB partial scores
    //   Qg/v2 : [1245184, +134217728)  Q (k2->k3), then v2 overlay (k4->k6)
    u16*   wt    = (u16*)d_ws;
    float* spart = (float*)((char*)d_ws + 196608);
    u16*   Qg    = (u16*)((char*)d_ws + 1245184);
    u16*   v2    = Qg;                                     // overlays Q (dead after k3)
    // d_out doubles as scratch for V and K (dead before k6 writes):
    u16*   Vg    = (u16*)d_out;
    u16*   Kg    = (u16*)d_out + 67108864;
    float* out   = (float*)d_out;

    kw_prep  <<<6,    256,  0, stream>>>(w_q, w_k, w_v, w_o, w1, w2, wt);
    k2_qkv   <<<2048, 1024, 0, stream>>>(v, wt, b_q, b_k, b_v, Qg, Kg, Vg);
    k3_scores<<<256,  1024, 0, stream>>>(Qg, Kg, spart);
    k4_attnout<<<512, 1024, 0, stream>>>(v, Vg, spart, wt, b_o, v2);
    k6_mlp   <<<2048, 1024, 0, stream>>>(v2, wt, b1, b2, out);
}

// Round 3
// 1232.450 us; speedup vs baseline: 1.2250x; 1.2250x over previous
//
#include <hip/hip_runtime.h>
#include <cstdint>
#include <cstddef>

#define DI __device__ __forceinline__

typedef unsigned short u16;
typedef u16 u16x8 __attribute__((ext_vector_type(8)));
typedef u16 u16x4 __attribute__((ext_vector_type(4)));
typedef float f32x4 __attribute__((ext_vector_type(4)));
typedef __bf16 bf16x8 __attribute__((ext_vector_type(8)));

constexpr float EPSf  = 1e-5f;
constexpr float SCALE = 1.0f / (5.656854249492381f * 256.0f); // 1/(sqrt(32)*H*W)

DI float bf2f(u16 u) { union { uint32_t i; float f; } v; v.i = ((uint32_t)u) << 16; return v.f; }
DI u16 f2bf(float f) {
    union { float f; uint32_t i; } v; v.f = f;
    uint32_t r = v.i + 0x7fffu + ((v.i >> 16) & 1u);
    return (u16)(r >> 16);
}
DI bf16x8 u2b(u16x8 u) { union { u16x8 a; bf16x8 b; } v; v.a = u; return v.b; }

DI f32x4 MFMA(bf16x8 a, bf16x8 b, f32x4 c) {
    return __builtin_amdgcn_mfma_f32_16x16x32_bf16(a, b, c, 0, 0, 0);
}

DI int region3(int x) { return x < 12 ? 0 : (x < 14 ? 1 : 2); }

// fast tanh-gelu: 0.5x(1+tanh(s(x+0.044715x^3))) == x*sigmoid(2s(x+...))
DI float gelu_f(float x) {
    float u = 1.5957691216f * x * (1.f + 0.044715f * x * x);
    return x * __builtin_amdgcn_rcpf(1.f + __expf(-u));
}

// ---------------------------------------------------------------------------
// KW: transpose 6 weights [c][d] f32 -> WT [d][c] bf16
// ---------------------------------------------------------------------------
__global__ __launch_bounds__(256) void kw_prep(
        const float* __restrict__ w_q, const float* __restrict__ w_k,
        const float* __restrict__ w_v, const float* __restrict__ w_o,
        const float* __restrict__ w1,  const float* __restrict__ w2,
        u16* __restrict__ wt) {
    __shared__ float lds[128 * 129];
    const float* W;
    switch (blockIdx.x) {
        case 0: W = w_q; break; case 1: W = w_k; break; case 2: W = w_v; break;
        case 3: W = w_o; break; case 4: W = w1;  break; default: W = w2;  break;
    }
    u16* O = wt + blockIdx.x * 16384;
    int tid = threadIdx.x;
    for (int i = 0; i < 16; i++) {
        int flat = i * 1024 + tid * 4;
        float4 vv = *(const float4*)(W + flat);
        int c = flat >> 7, d = flat & 127;
        lds[c * 129 + d + 0] = vv.x; lds[c * 129 + d + 1] = vv.y;
        lds[c * 129 + d + 2] = vv.z; lds[c * 129 + d + 3] = vv.w;
    }
    __syncthreads();
    for (int i = 0; i < 32; i++) {
        int flat2 = i * 512 + tid * 2;
        int d = flat2 >> 7, c = flat2 & 127;
        u16 a = f2bf(lds[c * 129 + d]);
        u16 b = f2bf(lds[(c + 1) * 129 + d]);
        uint32_t pk = (uint32_t)a | ((uint32_t)b << 16);
        *(uint32_t*)(O + flat2) = pk;
    }
}

// ---------------------------------------------------------------------------
// K2: per windowed-token. Coalesced 16B/lane loads (wave w, iter i reads the
//     full 1KB row of channel c=i*8+w), raw bf16 to LDS [c][xy] pitch 268.
//     Stats via contiguous row reads. Normalize folded into A-frag regs.
//     GEMM x3 with staged WT; epilogue staging wave-local.
//     Raw region overlaid by WTs(17408 u16) + stgw(17408 u16) in GEMM phase.
// ---------------------------------------------------------------------------
__global__ __launch_bounds__(512, 4) void k2_qkv(
        const float* __restrict__ v, const u16* __restrict__ wt,
        const float* __restrict__ b_q, const float* __restrict__ b_k,
        const float* __restrict__ b_v,
        u16* __restrict__ Qg, u16* __restrict__ Kg, u16* __restrict__ Vg) {
    __shared__ __align__(16) u16 Raw[34816];   // [c 128][xy] pitch 268 (34304 used)
    __shared__ float red[2][4][128];
    __shared__ float stats[2][128];

    int tid = threadIdx.x;
    int wtk = blockIdx.x;                       // windowed token id
    int b = wtk >> 8, n = (wtk >> 4) & 15, t = wtk & 15;
    int wi = n >> 2, wj = n & 3, ti = t >> 2, tj = t & 3;
    int si = (wi * 4 + ti + 2) & 15, sj = (wj * 4 + tj + 2) & 15; // roll -2
    const float* src = v + (size_t)(b * 256 + si * 16 + sj) * 32768;

    int wave = tid >> 6, lane = tid & 63;

    // load: wave w iter i covers channel c = i*8+w; lane reads 16B contiguous
    #pragma unroll
    for (int i = 0; i < 16; i++) {
        int c = i * 8 + wave;
        float4 f = *(const float4*)(src + c * 256 + lane * 4);
        u16x4 u; u.x = f2bf(f.x); u.y = f2bf(f.y); u.z = f2bf(f.z); u.w = f2bf(f.w);
        *(u16x4*)&Raw[c * 268 + lane * 4] = u;
    }
    __syncthreads();
    // stats: contiguous row reads (b64), per (c, quarter)
    {
        int c = tid & 127, p = tid >> 7;
        float s = 0.f, q = 0.f;
        #pragma unroll
        for (int k = 0; k < 16; k++) {
            u16x4 u = *(const u16x4*)&Raw[c * 268 + p * 64 + k * 4];
            float x0 = bf2f(u.x), x1 = bf2f(u.y), x2 = bf2f(u.z), x3 = bf2f(u.w);
            s += x0 + x1 + x2 + x3;
            q += x0 * x0 + x1 * x1 + x2 * x2 + x3 * x3;
        }
        red[0][p][c] = s; red[1][p][c] = q;
    }
    __syncthreads();
    if (tid < 128) {
        int c = tid;
        float s = red[0][0][c] + red[0][1][c] + red[0][2][c] + red[0][3][c];
        float q = red[1][0][c] + red[1][1][c] + red[1][2][c] + red[1][3][c];
        float mean = s * (1.f / 256.f);
        float var = q * (1.f / 256.f) - mean * mean;
        float a = rsqrtf(var + EPSf);
        stats[0][c] = a; stats[1][c] = -mean * a;
    }
    __syncthreads();

    // A-frag extraction with in-register normalization
    int lrow = lane & 15, quad = lane >> 4;
    bf16x8 afr[2][4];
    #pragma unroll
    for (int kt = 0; kt < 4; kt++) {
        float sa[8], sb[8];
        #pragma unroll
        for (int j = 0; j < 8; j++) {
            int c = kt * 32 + quad * 8 + j;
            sa[j] = stats[0][c]; sb[j] = stats[1][c];
        }
        #pragma unroll
        for (int mi = 0; mi < 2; mi++) {
            int xy = (wave * 2 + mi) * 16 + lrow;
            u16x8 o;
            #pragma unroll
            for (int j = 0; j < 8; j++) {
                int c = kt * 32 + quad * 8 + j;
                o[j] = f2bf(fmaf(bf2f(Raw[c * 268 + xy]), sa[j], sb[j]));
            }
            afr[mi][kt] = u2b(o);
        }
    }
    __syncthreads();   // all waves extracted; Raw is now overlay region

    u16* WTs  = Raw;                     // 128 rows x pitch 136
    u16* stgw = Raw + 17408 + wave * 2176;   // per-wave 16 x pitch 136
    for (int w = 0; w < 3; w++) {
        const u16* WTp = wt + w * 16384;
        const float* bias = (w == 0) ? b_q : (w == 1) ? b_k : b_v;
        u16* O = ((w == 0) ? Qg : (w == 1) ? Kg : Vg) + (size_t)wtk * 32768;
        if (w) __syncthreads();          // prior GEMM done reading WTs
        #pragma unroll
        for (int i = 0; i < 4; i++) {
            int flat = i * 4096 + tid * 8;
            *(u16x8*)&WTs[(flat >> 7) * 136 + (flat & 127)] =
                *(const u16x8*)&WTp[flat];
        }
        __syncthreads();
        f32x4 acc[2][8];
        #pragma unroll
        for (int mi = 0; mi < 2; mi++)
            #pragma unroll
            for (int nt = 0; nt < 8; nt++) acc[mi][nt] = (f32x4){0.f, 0.f, 0.f, 0.f};
        #pragma unroll
        for (int kt = 0; kt < 4; kt++) {
            #pragma unroll
            for (int nt = 0; nt < 8; nt++) {
                bf16x8 bfr = *(const bf16x8*)&WTs[(nt * 16 + lrow) * 136 + kt * 32 + quad * 8];
                acc[0][nt] = MFMA(afr[0][kt], bfr, acc[0][nt]);
                acc[1][nt] = MFMA(afr[1][kt], bfr, acc[1][nt]);
            }
        }
        #pragma unroll
        for (int mi = 0; mi < 2; mi++) {
            int mt = wave * 2 + mi;
            #pragma unroll
            for (int nt = 0; nt < 8; nt++) {
                int d = nt * 16 + lrow;
                float bv = bias[d];
                #pragma unroll
                for (int r = 0; r < 4; r++)
                    stgw[(quad * 4 + r) * 136 + d] = f2bf(acc[mi][nt][r] + bv);
            }
            // wave-local staging: no barrier needed
            #pragma unroll
            for (int ro = 0; ro < 4; ro++) {
                int flat = ro * 512 + lane * 8;
                *(u16x8*)&O[mt * 2048 + flat] =
                    *(const u16x8*)&stgw[(flat >> 7) * 136 + (flat & 127)];
            }
        }
    }
}

// ---------------------------------------------------------------------------
// K3: partial scores per (b, window, xy-half). Fragments straight from global.
//     16 waves = 4 heads x 4 xy-subchunks; cross-wave f32x4 reduce in LDS.
// ---------------------------------------------------------------------------
__global__ __launch_bounds__(1024, 4) void k3_scores(
        const u16* __restrict__ Qg, const u16* __restrict__ Kg,
        float* __restrict__ spart) {
    __shared__ f32x4 red3[3][4][64];
    int tid = threadIdx.x;
    int bid = blockIdx.x;                   // 256 = b(8) * n(16) * half(2)
    int b = bid >> 5, n = (bid >> 1) & 15, half = bid & 1;
    int wtb = (b * 16 + n) * 16;
    int lane = tid & 63, wave = tid >> 6;   // 16 waves
    int head = wave & 3, sub = wave >> 2;   // head 0..3, xy-subchunk 0..3
    int lrow = lane & 15, quad = lane >> 4;
    int xyb = half * 128 + sub * 32;
    const u16* Qp = Qg + (size_t)(wtb + lrow) * 32768 + (size_t)xyb * 128 + head * 32 + quad * 8;
    const u16* Kp = Kg + (size_t)(wtb + lrow) * 32768 + (size_t)xyb * 128 + head * 32 + quad * 8;
    f32x4 acc = {0.f, 0.f, 0.f, 0.f};
    #pragma unroll 4
    for (int kt = 0; kt < 32; kt++) {
        bf16x8 aq = *(const bf16x8*)(Qp + kt * 128);
        bf16x8 bk = *(const bf16x8*)(Kp + kt * 128);
        acc = MFMA(aq, bk, acc);
    }
    if (sub) red3[sub - 1][head][lane] = acc;
    __syncthreads();
    if (sub == 0) {
        f32x4 a0 = red3[0][head][lane];
        f32x4 a1 = red3[1][head][lane];
        f32x4 a2 = red3[2][head][lane];
        acc = acc + a0 + a1 + a2;
        float* sp = spart + (size_t)(((half * 8 + b) * 16 + n) * 4 + head) * 256;
        for (int r = 0; r < 4; r++) sp[(quad * 4 + r) * 16 + lrow] = acc[r];
    }
}

// ---------------------------------------------------------------------------
// K4: softmax+mask, PV directly into MFMA A-frags (no Obuf), Wo GEMM,
//     + residual v -> v2 bf16 [tok][xy][c]. Vc chunk-swizzled (conflict-free
//     PV reads). LDS ~70KB -> 2 blocks/CU.
// ---------------------------------------------------------------------------
__global__ __launch_bounds__(512, 4) void k4_attnout(
        const float* __restrict__ v, const u16* __restrict__ Vg,
        const float* __restrict__ spart, const u16* __restrict__ wt,
        const float* __restrict__ b_o, u16* __restrict__ v2) {
    __shared__ __align__(16) u16 Vc[32768];    // [s16][xyl16][c128], chunk^=(xyl&7)
    __shared__ float attn[4][16][16];
    int tid = threadIdx.x;
    int bid = blockIdx.x;              // 512
    int b = bid >> 6, n = (bid >> 2) & 15, qtr = bid & 3;
    int wi = n >> 2, wj = n & 3;
    int wtb = (b * 16 + n) * 16;

    if (tid < 64) {
        int h = tid >> 4, t = tid & 15;
        int it = wi * 4 + (t >> 2) , jt = wj * 4 + (t & 3);
        int rt = region3(it) * 3 + region3(jt);
        const float* sp0 = spart + (size_t)(((0 + b) * 16 + n) * 4 + h) * 256 + t * 16;
        const float* sp1 = spart + (size_t)(((8 + b) * 16 + n) * 4 + h) * 256 + t * 16;
        float vals[16]; float mx = -1e30f;
        for (int s = 0; s < 16; s++) {
            int is = wi * 4 + (s >> 2), js = wj * 4 + (s & 3);
            int rs = region3(is) * 3 + region3(js);
            float sc = (sp0[s] + sp1[s]) * SCALE + (rs == rt ? 0.f : -1e9f);
            vals[s] = sc; mx = fmaxf(mx, sc);
        }
        float sum = 0.f;
        for (int s = 0; s < 16; s++) { vals[s] = __expf(vals[s] - mx); sum += vals[s]; }
        float inv = 1.f / sum;
        for (int s = 0; s < 16; s++) attn[h][t][s] = vals[s] * inv;
    }
    __syncthreads();

    int lane = tid & 63, wave = tid >> 6;
    int lrow = lane & 15, quad = lane >> 4;
    const u16* WoT = wt + 3 * 16384;

    for (int sub = 0; sub < 4; sub++) {
        int xyb = qtr * 64 + sub * 16;
        if (sub) __syncthreads();          // prior epilogue stgw reads done
        // V load, chunk-swizzled within each (s, xyl) row
        #pragma unroll
        for (int it = 0; it < 8; it++) {
            int flat = (it * 512 + tid) * 8;
            int s = flat >> 11, rem = flat & 2047;
            int xyl = rem >> 7, ch = (rem & 127) >> 3;
            *(u16x8*)&Vc[s * 2048 + xyl * 128 + ((ch ^ (xyl & 7)) << 3)] =
                *(const u16x8*)&Vg[(size_t)(wtb + s) * 32768 + xyb * 128 + rem];
        }
        __syncthreads();
        // PV directly into A-frags: row = xyl = lrow, c-slice = kt*32+quad*8
        bf16x8 pa[2][4];
        int t0 = wave * 2, t1 = wave * 2 + 1;
        #pragma unroll
        for (int kt = 0; kt < 4; kt++) {
            float oa[8], ob[8];
            #pragma unroll
            for (int j = 0; j < 8; j++) { oa[j] = 0.f; ob[j] = 0.f; }
            #pragma unroll
            for (int s = 0; s < 16; s++) {
                float a0 = attn[kt][t0][s], a1 = attn[kt][t1][s];
                u16x8 vv = *(const u16x8*)&Vc[s * 2048 + lrow * 128 +
                                              (((kt * 4 + quad) ^ (lrow & 7)) << 3)];
                #pragma unroll
                for (int j = 0; j < 8; j++) {
                    float x = bf2f(vv[j]);
                    oa[j] = fmaf(a0, x, oa[j]);
                    ob[j] = fmaf(a1, x, ob[j]);
                }
            }
            u16x8 ua, ub;
            #pragma unroll
            for (int j = 0; j < 8; j++) { ua[j] = f2bf(oa[j]); ub[j] = f2bf(ob[j]); }
            pa[0][kt] = u2b(ua); pa[1][kt] = u2b(ub);
        }
        __syncthreads();                   // all PV reads of Vc done
        // Wo GEMM + residual
        f32x4 acc[2][8];
        #pragma unroll
        for (int mi = 0; mi < 2; mi++)
            #pragma unroll
            for (int nt = 0; nt < 8; nt++) acc[mi][nt] = (f32x4){0.f, 0.f, 0.f, 0.f};
        #pragma unroll
        for (int kt = 0; kt < 4; kt++) {
            #pragma unroll
            for (int nt = 0; nt < 8; nt++) {
                bf16x8 bfr = *(const bf16x8*)&WoT[(nt * 16 + lrow) * 128 + kt * 32 + quad * 8];
                acc[0][nt] = MFMA(pa[0][kt], bfr, acc[0][nt]);
                acc[1][nt] = MFMA(pa[1][kt], bfr, acc[1][nt]);
            }
        }
        u16* stgw = Vc + wave * 2176;      // per-wave 16 x pitch 136 (Vc dead)
        #pragma unroll
        for (int mi = 0; mi < 2; mi++) {
            int mt = wave * 2 + mi;        // token t within window
            int sd = (((wi * 4 + (mt >> 2) + 2) & 15) << 4) | ((wj * 4 + (mt & 3) + 2) & 15);
            size_t tokbase = (size_t)(b * 256 + sd) * 32768;
            #pragma unroll
            for (int nt = 0; nt < 8; nt++) {
                int cc = nt * 16 + lrow;
                float bv = b_o[cc];
                float4 res = *(const float4*)&v[tokbase + (size_t)cc * 256 + xyb + quad * 4];
                stgw[(quad * 4 + 0) * 136 + cc] = f2bf(acc[mi][nt][0] + bv + res.x);
                stgw[(quad * 4 + 1) * 136 + cc] = f2bf(acc[mi][nt][1] + bv + res.y);
                stgw[(quad * 4 + 2) * 136 + cc] = f2bf(acc[mi][nt][2] + bv + res.z);
                stgw[(quad * 4 + 3) * 136 + cc] = f2bf(acc[mi][nt][3] + bv + res.w);
            }
            // wave-local staging: no barrier needed
            size_t obase = tokbase + (size_t)xyb * 128;
            #pragma unroll
            for (int ro = 0; ro < 4; ro++) {
                int flat = ro * 512 + lane * 8;
                *(u16x8*)&v2[obase + flat] =
                    *(const u16x8*)&stgw[(flat >> 7) * 136 + (flat & 127)];
            }
        }
    }
}

// ---------------------------------------------------------------------------
// K6: per token: stats from raw, W1 GEMM with in-register normalize + gelu,
//     W2 GEMM, + raw residual -> out f32 [c][xy]. Normalize pass eliminated.
// ---------------------------------------------------------------------------
__global__ __launch_bounds__(512, 4) void k6_mlp(
        const u16* __restrict__ v2, const u16* __restrict__ wt,
        const float* __restrict__ b1, const float* __restrict__ b2,
        float* __restrict__ out) {
    __shared__ __align__(16) u16 Nbuf[256 * 136];   // RAW v2 tile [xy][c]
    __shared__ __align__(16) u16 Hbuf[256 * 136];   // W1T stage, then H
    __shared__ float red[2][4][128];
    __shared__ float stats[2][128];
    int tid = threadIdx.x;
    size_t tok = blockIdx.x;
    const u16* src = v2 + tok * 32768;

    #pragma unroll
    for (int it = 0; it < 8; it++) {
        int flat = (it * 512 + tid) * 8;
        int xy = flat >> 7, c = flat & 127;
        *(u16x8*)&Nbuf[xy * 136 + c] = *(const u16x8*)&src[flat];
    }
    {   // stage W1T into Hbuf rows 0..127 (independent of Nbuf/stats)
        const u16* W1T = wt + 4 * 16384;
        #pragma unroll
        for (int i = 0; i < 4; i++) {
            int flat = i * 4096 + tid * 8;
            *(u16x8*)&Hbuf[(flat >> 7) * 136 + (flat & 127)] = *(const u16x8*)&W1T[flat];
        }
    }
    __syncthreads();
    {
        int c = tid & 127, p = tid >> 7;
        float s = 0.f, q = 0.f;
        for (int k = 0; k < 64; k++) {
            float x = bf2f(Nbuf[(p * 64 + k) * 136 + c]);
            s += x; q += x * x;
        }
        red[0][p][c] = s; red[1][p][c] = q;
    }
    __syncthreads();
    if (tid < 128) {
        int c = tid;
        float s = red[0][0][c] + red[0][1][c] + red[0][2][c] + red[0][3][c];
        float q = red[1][0][c] + red[1][1][c] + red[1][2][c] + red[1][3][c];
        float mean = s * (1.f / 256.f);
        float var = q * (1.f / 256.f) - mean * mean;
        float a = rsqrtf(var + EPSf);
        stats[0][c] = a; stats[1][c] = -mean * a;
    }
    __syncthreads();

    int wave = tid >> 6, lane = tid & 63;
    int lrow = lane & 15, quad = lane >> 4;
    const u16* W2T = wt + 5 * 16384;

    // GEMM1 (A = normalized-in-regs raw, B = staged W1T) + gelu -> Hbuf
    {
        bf16x8 afr[2][4];
        #pragma unroll
        for (int kt = 0; kt < 4; kt++) {
            float sa[8], sb[8];
            #pragma unroll
            for (int j = 0; j < 8; j++) {
                int c = kt * 32 + quad * 8 + j;
                sa[j] = stats[0][c]; sb[j] = stats[1][c];
            }
            #pragma unroll
            for (int mi = 0; mi < 2; mi++) {
                int mt = wave * 2 + mi;
                u16x8 raw = *(const u16x8*)&Nbuf[(mt * 16 + lrow) * 136 + kt * 32 + quad * 8];
                u16x8 o;
                #pragma unroll
                for (int j = 0; j < 8; j++)
                    o[j] = f2bf(fmaf(bf2f(raw[j]), sa[j], sb[j]));
                afr[mi][kt] = u2b(o);
            }
        }
        f32x4 acc[2][8];
        #pragma unroll
        for (int mi = 0; mi < 2; mi++)
            #pragma unroll
            for (int nt = 0; nt < 8; nt++) acc[mi][nt] = (f32x4){0.f, 0.f, 0.f, 0.f};
        #pragma unroll
        for (int kt = 0; kt < 4; kt++) {
            #pragma unroll
            for (int nt = 0; nt < 8; nt++) {
                bf16x8 bfr = *(const bf16x8*)&Hbuf[(nt * 16 + lrow) * 136 + kt * 32 + quad * 8];
                acc[0][nt] = MFMA(afr[0][kt], bfr, acc[0][nt]);
                acc[1][nt] = MFMA(afr[1][kt], bfr, acc[1][nt]);
            }
        }
        __syncthreads();   // all waves done reading W1T before H overwrites it
        #pragma unroll
        for (int mi = 0; mi < 2; mi++) {
            int mt = wave * 2 + mi;
            #pragma unroll
            for (int nt = 0; nt < 8; nt++) {
                int c = nt * 16 + lrow;
                float bv = b1[c];
                #pragma unroll
                for (int r = 0; r < 4; r++) {
                    float x = acc[mi][nt][r] + bv;
                    Hbuf[(mt * 16 + quad * 4 + r) * 136 + c] = f2bf(gelu_f(x));
                }
            }
        }
    }
    // H rows wave-local -> no barrier
    {
        bf16x8 afr[2][4];
        #pragma unroll
        for (int mi = 0; mi < 2; mi++) {
            int mt = wave * 2 + mi;
            #pragma unroll
            for (int kt = 0; kt < 4; kt++)
                afr[mi][kt] = *(const bf16x8*)&Hbuf[(mt * 16 + lrow) * 136 + kt * 32 + quad * 8];
        }
        f32x4 acc[2][8];
        #pragma unroll
        for (int mi = 0; mi < 2; mi++)
            #pragma unroll
            for (int nt = 0; nt < 8; nt++) acc[mi][nt] = (f32x4){0.f, 0.f, 0.f, 0.f};
        #pragma unroll
        for (int kt = 0; kt < 4; kt++) {
            #pragma unroll
            for (int nt = 0; nt < 8; nt++) {
                bf16x8 bfr = *(const bf16x8*)&W2T[(nt * 16 + lrow) * 128 + kt * 32 + quad * 8];
                acc[0][nt] = MFMA(afr[0][kt], bfr, acc[0][nt]);
                acc[1][nt] = MFMA(afr[1][kt], bfr, acc[1][nt]);
            }
        }
        #pragma unroll
        for (int mi = 0; mi < 2; mi++) {
            int mt = wave * 2 + mi;
            #pragma unroll
            for (int nt = 0; nt < 8; nt++) {
                int c = nt * 16 + lrow;
                float bv = b2[c];
                f32x4 o4;
                #pragma unroll
                for (int r = 0; r < 4; r++) {
                    int m = mt * 16 + quad * 4 + r;
                    o4[r] = acc[mi][nt][r] + bv + bf2f(Nbuf[m * 136 + c]);  // raw residual
                }
                *(f32x4*)&out[tok * 32768 + (size_t)c * 256 + mt * 16 + quad * 4] = o4;
            }
        }
    }
}

// ---------------------------------------------------------------------------
extern "C" void kernel_launch(void* const* d_in, const int* in_sizes, int n_in,
                              void* d_out, int out_size, void* d_ws, size_t ws_size,
                              hipStream_t stream) {
    const float* v   = (const float*)d_in[0];
    const float* w_q = (const float*)d_in[1];
    const float* b_q = (const float*)d_in[2];
    const float* w_k = (const float*)d_in[3];
    const float* b_k = (const float*)d_in[4];
    const float* w_v = (const float*)d_in[5];
    const float* b_v = (const float*)d_in[6];
    const float* w_o = (const float*)d_in[7];
    const float* b_o = (const float*)d_in[8];
    const float* w1  = (const float*)d_in[9];
    const float* b1  = (const float*)d_in[10];
    const float* w2  = (const float*)d_in[11];
    const float* b2  = (const float*)d_in[12];

    // workspace layout (~135.5 MB):
    //   wt    : [0, 196608)            6 x 128x128 bf16 transposed weights
    //   spart : [196608, 1245184)      2*8*16*4*256 floats = 1 MB partial scores
    //   Qg/v2 : [1245184, +134217728)  Q (k2->k3), then v2 overlay (k4->k6)
    u16*   wt    = (u16*)d_ws;
    float* spart = (float*)((char*)d_ws + 196608);
    u16*   Qg    = (u16*)((char*)d_ws + 1245184);
    u16*   v2    = Qg;                                     // overlays Q (dead after k3)
    // d_out doubles as scratch for V and K (dead before k6 writes):
    u16*   Vg    = (u16*)d_out;
    u16*   Kg    = (u16*)d_out + 67108864;
    float* out   = (float*)d_out;

    kw_prep  <<<6,    256,  0, stream>>>(w_q, w_k, w_v, w_o, w1, w2, wt);
    k2_qkv   <<<2048, 512,  0, stream>>>(v, wt, b_q, b_k, b_v, Qg, Kg, Vg);
    k3_scores<<<256,  1024, 0, stream>>>(Qg, Kg, spart);
    k4_attnout<<<512, 512,  0, stream>>>(v, Vg, spart, wt, b_o, v2);
    k6_mlp   <<<2048, 512,  0, stream>>>(v2, wt, b1, b2, out);
}